// Round 1
// baseline (13715.335 us; speedup 1.0000x reference)
//
#include <hip/hip_runtime.h>
#include <cstdint>
#include <cstddef>

// Problem: B=64, T=512, D_IN=1024, UNITS=1024
//   phase 1: xk = x @ kernel  -> written into d_out  [32768 x 1024]
//   phase 2: persistent scan kernel, in-place on d_out:
//            h_t = relu(xk_t + h_{t-1} @ R)
//
// Phase-2 geometry: 4 clusters (16 batches = one MFMA M-tile each)
//                   x 32 col-group WGs (32 cols each) = 128 WGs, 256 thr.
//   wave (4/WG) = k-quarter (k-span 256); W frags persistent in VGPRs.
//   h carried as split bf16 hi+lo pair in ws (fragment-layout), ping-pong.
//   Per-cluster barrier: agent-scope atomic counter + threadfence.
// 128 WGs <= 256 CUs -> whole grid trivially co-resident, spin-safe.

typedef __attribute__((ext_vector_type(8))) short short8;
typedef __attribute__((ext_vector_type(4))) float f32x4;

static __device__ __forceinline__ unsigned short f2bf_rne(float f) {
  unsigned u = __float_as_uint(f);
  u += 0x7fffu + ((u >> 16) & 1u);
  return (unsigned short)(u >> 16);
}

// ---------------------------------------------------------------- phase 1
// C[m][n] = sum_k A[m][k] B[k][n], M=32768 N=1024 K=1024, fp32 in, fp32 out,
// bf16 MFMA 16x16x32. Tile 128x128, 4 waves of 64x64 (4x4 16x16 subtiles).
__global__ __launch_bounds__(256) void xproj_kernel(const float* __restrict__ x,
                                                    const float* __restrict__ kern,
                                                    float* __restrict__ out) {
  // stride 40 bf16 = 80 B: 16B-aligned rows, conflict-benign frag reads
  __shared__ unsigned short Abuf[128 * 40];
  __shared__ unsigned short Bbuf[128 * 40];
  const int tid = threadIdx.x;
  const int lane = tid & 63;
  const int wv = tid >> 6;
  const int q = lane >> 4;
  const int lr = lane & 15;
  const int wm = (wv >> 1) * 64;
  const int wn = (wv & 1) * 64;
  const long rowbase = (long)blockIdx.y * 128;
  const int colbase = blockIdx.x * 128;

  f32x4 acc[4][4];
#pragma unroll
  for (int i = 0; i < 4; i++)
#pragma unroll
    for (int j = 0; j < 4; j++) acc[i][j] = (f32x4)0.f;

  for (int kb = 0; kb < 1024; kb += 32) {
    // stage A tile [128 m][32 k] as bf16
#pragma unroll
    for (int r = 0; r < 4; ++r) {
      int idx = tid + r * 256;
      int m = idx >> 3;
      int kk = (idx & 7) * 4;
      float4 v = *(const float4*)(x + (rowbase + m) * 1024 + kb + kk);
      ushort4 w4;
      w4.x = f2bf_rne(v.x); w4.y = f2bf_rne(v.y);
      w4.z = f2bf_rne(v.z); w4.w = f2bf_rne(v.w);
      *(ushort4*)&Abuf[m * 40 + kk] = w4;
    }
    // stage B tile transposed: Bbuf[n][k]
#pragma unroll
    for (int r = 0; r < 4; ++r) {
      int idx = tid + r * 256;
      int kr = idx >> 5;          // 0..31
      int nn = (idx & 31) * 4;
      float4 v = *(const float4*)(kern + (long)(kb + kr) * 1024 + colbase + nn);
      Bbuf[(nn + 0) * 40 + kr] = f2bf_rne(v.x);
      Bbuf[(nn + 1) * 40 + kr] = f2bf_rne(v.y);
      Bbuf[(nn + 2) * 40 + kr] = f2bf_rne(v.z);
      Bbuf[(nn + 3) * 40 + kr] = f2bf_rne(v.w);
    }
    __syncthreads();
    short8 af[4], bfr[4];
#pragma unroll
    for (int i = 0; i < 4; i++)
      af[i] = *(const short8*)&Abuf[(wm + i * 16 + lr) * 40 + q * 8];
#pragma unroll
    for (int j = 0; j < 4; j++)
      bfr[j] = *(const short8*)&Bbuf[(wn + j * 16 + lr) * 40 + q * 8];
#pragma unroll
    for (int i = 0; i < 4; i++)
#pragma unroll
      for (int j = 0; j < 4; j++)
        acc[i][j] = __builtin_amdgcn_mfma_f32_16x16x32_bf16(af[i], bfr[j], acc[i][j], 0, 0, 0);
    __syncthreads();
  }
  // epilogue: C/D layout col = lane&15, row = (lane>>4)*4 + reg
#pragma unroll
  for (int i = 0; i < 4; i++) {
#pragma unroll
    for (int r = 0; r < 4; r++) {
      long row = rowbase + wm + i * 16 + q * 4 + r;
      float* op = out + row * 1024 + colbase + wn + lr;
#pragma unroll
      for (int j = 0; j < 4; j++) op[j * 16] = acc[i][j][r];
    }
  }
}

// ---------------------------------------------------------------- phase 2
// hbuf layout (u16): [parity 2][part hi/lo 2][cluster 4][16384]
//   element (m,k) at (k>>3)*128 + m*8 + (k&7)  -> A-frag dwordx4-ready.
__global__ __launch_bounds__(256) void rnn_scan_kernel(const float* __restrict__ R,
                                                       float* __restrict__ out,
                                                       unsigned short* __restrict__ hbuf,
                                                       unsigned int* __restrict__ flags) {
  const int tid = threadIdx.x;
  const int lane = tid & 63;
  const int wv = tid >> 6;        // k-quarter 0..3
  const int q = lane >> 4;
  const int lr = lane & 15;
  const int cluster = blockIdx.x & 3;
  const int cg = blockIdx.x >> 2; // col-group 0..31

  // persistent W fragments: B[k][n] frag: lane n=lr, k = q*8+j
  short8 w[2][8];
#pragma unroll
  for (int nt = 0; nt < 2; nt++) {
    int col = cg * 32 + nt * 16 + lr;
#pragma unroll
    for (int cc = 0; cc < 8; cc++) {
      int k0 = wv * 256 + cc * 32 + q * 8;
      short8 t8;
#pragma unroll
      for (int j = 0; j < 8; j++)
        t8[j] = (short)f2bf_rne(R[(long)(k0 + j) * 1024 + col]);
      w[nt][cc] = t8;
    }
  }

  __shared__ float red[4 * 2 * 64 * 4];  // [wave][ntile][lane][reg] 8 KB
  unsigned int* myflag = flags + cluster * 64;  // 256B-padded counters
  const int m_lo = tid >> 5;   // 0..7
  const int myn = tid & 31;

  for (int t = 0; t < 512; ++t) {
    f32x4 acc0 = (f32x4)0.f, acc1 = (f32x4)0.f;
    if (t > 0) {
      const unsigned short* hb = hbuf + (size_t)((((t - 1) & 1) * 2 + 0) * 4 + cluster) * 16384;
      const unsigned short* lb = hbuf + (size_t)((((t - 1) & 1) * 2 + 1) * 4 + cluster) * 16384;
      short8 ah[8], al[8];
#pragma unroll
      for (int cc = 0; cc < 8; cc++) {
        int kc = wv * 8 + cc;
        int off = (kc * 4 + q) * 128 + lr * 8;
        ah[cc] = *(const short8*)(hb + off);
        al[cc] = *(const short8*)(lb + off);
      }
#pragma unroll
      for (int cc = 0; cc < 8; cc++) {
        acc0 = __builtin_amdgcn_mfma_f32_16x16x32_bf16(ah[cc], w[0][cc], acc0, 0, 0, 0);
        acc0 = __builtin_amdgcn_mfma_f32_16x16x32_bf16(al[cc], w[0][cc], acc0, 0, 0, 0);
        acc1 = __builtin_amdgcn_mfma_f32_16x16x32_bf16(ah[cc], w[1][cc], acc1, 0, 0, 0);
        acc1 = __builtin_amdgcn_mfma_f32_16x16x32_bf16(al[cc], w[1][cc], acc1, 0, 0, 0);
      }
    }
    // 4-way k-split reduction through LDS
    *(f32x4*)&red[((wv * 2 + 0) * 64 + lane) * 4] = acc0;
    *(f32x4*)&red[((wv * 2 + 1) * 64 + lane) * 4] = acc1;
    __syncthreads();
#pragma unroll
    for (int mi = 0; mi < 2; ++mi) {
      int m = m_lo + mi * 8;
      int nt = myn >> 4;
      int ln = (myn & 15) + ((m >> 2) & 3) * 16;
      int r = m & 3;
      float s = red[((0 * 2 + nt) * 64 + ln) * 4 + r] + red[((1 * 2 + nt) * 64 + ln) * 4 + r] +
                red[((2 * 2 + nt) * 64 + ln) * 4 + r] + red[((3 * 2 + nt) * 64 + ln) * 4 + r];
      long orow = (long)(cluster * 16 + m) * 512 + t;
      float* op = out + orow * 1024 + cg * 32 + myn;
      float h = s + *op;          // xk_t (phase-1 result, owned by this WG)
      h = fmaxf(h, 0.0f);
      *op = h;                    // final output h_t, in place
      unsigned short hi = f2bf_rne(h);
      float hf = __uint_as_float(((unsigned)hi) << 16);
      unsigned short lo = f2bf_rne(h - hf);
      int k = cg * 32 + myn;
      int off = (k >> 3) * 128 + m * 8 + (k & 7);
      hbuf[(size_t)(((t & 1) * 2 + 0) * 4 + cluster) * 16384 + off] = hi;
      hbuf[(size_t)(((t & 1) * 2 + 1) * 4 + cluster) * 16384 + off] = lo;
    }
    if (t < 511) {
      __threadfence();            // release my stores to agent scope
      __syncthreads();
      if (tid == 0) {
        __hip_atomic_fetch_add(myflag, 1u, __ATOMIC_RELEASE, __HIP_MEMORY_SCOPE_AGENT);
        unsigned target = 32u * (unsigned)(t + 1);
        while (__hip_atomic_load(myflag, __ATOMIC_ACQUIRE, __HIP_MEMORY_SCOPE_AGENT) < target) {
          __builtin_amdgcn_s_sleep(1);
        }
      }
      __syncthreads();
      __threadfence();            // acquire side: invalidate for all threads
    }
  }
}

extern "C" void kernel_launch(void* const* d_in, const int* in_sizes, int n_in,
                              void* d_out, int out_size, void* d_ws, size_t ws_size,
                              hipStream_t stream) {
  const float* x = (const float*)d_in[0];
  const float* kern = (const float*)d_in[1];
  const float* R = (const float*)d_in[2];
  float* out = (float*)d_out;

  // ws: [0, 512KB) h ping-pong hi/lo buffers; [512KB, +1KB) barrier flags
  unsigned short* hbuf = (unsigned short*)d_ws;
  unsigned int* flags = (unsigned int*)((char*)d_ws + (size_t)2 * 2 * 4 * 16384 * sizeof(unsigned short));
  hipMemsetAsync(flags, 0, 1024, stream);

  dim3 g1(8, 256), b1(256);
  xproj_kernel<<<g1, b1, 0, stream>>>(x, kern, out);
  rnn_scan_kernel<<<128, 256, 0, stream>>>(R, out, hbuf, flags);
}

// Round 3
// 2292.650 us; speedup vs baseline: 5.9823x; 5.9823x over previous
//
#include <hip/hip_runtime.h>
#include <cstdint>
#include <cstddef>

// Problem: B=64, T=512, D_IN=1024, UNITS=1024
//   phase 1: xk = x @ kernel  -> written into d_out  [32768 x 1024]
//   phase 2: persistent scan kernel, in-place on d_out:
//            h_t = relu(xk_t + h_{t-1} @ R)
//
// Phase-2 geometry: 4 clusters (16 batches = one MFMA M-tile each)
//                   x 32 col-group WGs (32 cols each) = 128 WGs, 256 thr.
// R3: no cache-maintenance anywhere (no threadfence/acq/rel). h exchanged
// via sc0 sc1 (system-scope, coherence-point) ld/st; barrier flag via
// no-return global_atomic_add sc1 + sc0 sc1 poll load with fused waitcnt.
// h-frag loads + s_waitcnt vmcnt(0) fused in ONE asm block so MFMA cannot
// consume in-flight registers (R2's hang/correctness bugs fixed).

typedef __attribute__((ext_vector_type(8))) short short8;
typedef __attribute__((ext_vector_type(4))) float f32x4;

static __device__ __forceinline__ unsigned short f2bf_rne(float f) {
  unsigned u = __float_as_uint(f);
  u += 0x7fffu + ((u >> 16) & 1u);
  return (unsigned short)(u >> 16);
}

static __device__ __forceinline__ void st_g16_cc(unsigned short* p, unsigned short val) {
  unsigned v32 = val;
  asm volatile("global_store_short %0, %1, off sc0 sc1"
               :: "v"(p), "v"(v32) : "memory");
}
static __device__ __forceinline__ void wait_vm0() {
  asm volatile("s_waitcnt vmcnt(0)" ::: "memory");
}
// coherence-point flag ops: visibility without any cache-maintenance
static __device__ __forceinline__ unsigned ld_flag_cc(const unsigned int* p) {
  unsigned v;
  asm volatile("global_load_dword %0, %1, off sc0 sc1\n\t"
               "s_waitcnt vmcnt(0)"
               : "=v"(v) : "v"(p) : "memory");
  return v;
}
static __device__ __forceinline__ void flag_add_cc(unsigned int* p, unsigned val) {
  asm volatile("global_atomic_add %0, %1, off sc1"
               :: "v"(p), "v"(val) : "memory");
}

// ---------------------------------------------------------------- phase 1
__global__ __launch_bounds__(256) void xproj_kernel(const float* __restrict__ x,
                                                    const float* __restrict__ kern,
                                                    float* __restrict__ out) {
  __shared__ unsigned short Abuf[128 * 40];
  __shared__ unsigned short Bbuf[128 * 40];
  const int tid = threadIdx.x;
  const int lane = tid & 63;
  const int wv = tid >> 6;
  const int q = lane >> 4;
  const int lr = lane & 15;
  const int wm = (wv >> 1) * 64;
  const int wn = (wv & 1) * 64;
  const long rowbase = (long)blockIdx.y * 128;
  const int colbase = blockIdx.x * 128;

  f32x4 acc[4][4];
#pragma unroll
  for (int i = 0; i < 4; i++)
#pragma unroll
    for (int j = 0; j < 4; j++) acc[i][j] = (f32x4)0.f;

  for (int kb = 0; kb < 1024; kb += 32) {
#pragma unroll
    for (int r = 0; r < 4; ++r) {
      int idx = tid + r * 256;
      int m = idx >> 3;
      int kk = (idx & 7) * 4;
      float4 v = *(const float4*)(x + (rowbase + m) * 1024 + kb + kk);
      ushort4 w4;
      w4.x = f2bf_rne(v.x); w4.y = f2bf_rne(v.y);
      w4.z = f2bf_rne(v.z); w4.w = f2bf_rne(v.w);
      *(ushort4*)&Abuf[m * 40 + kk] = w4;
    }
#pragma unroll
    for (int r = 0; r < 4; ++r) {
      int idx = tid + r * 256;
      int kr = idx >> 5;
      int nn = (idx & 31) * 4;
      float4 v = *(const float4*)(kern + (long)(kb + kr) * 1024 + colbase + nn);
      Bbuf[(nn + 0) * 40 + kr] = f2bf_rne(v.x);
      Bbuf[(nn + 1) * 40 + kr] = f2bf_rne(v.y);
      Bbuf[(nn + 2) * 40 + kr] = f2bf_rne(v.z);
      Bbuf[(nn + 3) * 40 + kr] = f2bf_rne(v.w);
    }
    __syncthreads();
    short8 af[4], bfr[4];
#pragma unroll
    for (int i = 0; i < 4; i++)
      af[i] = *(const short8*)&Abuf[(wm + i * 16 + lr) * 40 + q * 8];
#pragma unroll
    for (int j = 0; j < 4; j++)
      bfr[j] = *(const short8*)&Bbuf[(wn + j * 16 + lr) * 40 + q * 8];
#pragma unroll
    for (int i = 0; i < 4; i++)
#pragma unroll
      for (int j = 0; j < 4; j++)
        acc[i][j] = __builtin_amdgcn_mfma_f32_16x16x32_bf16(af[i], bfr[j], acc[i][j], 0, 0, 0);
    __syncthreads();
  }
#pragma unroll
  for (int i = 0; i < 4; i++) {
#pragma unroll
    for (int r = 0; r < 4; r++) {
      long row = rowbase + wm + i * 16 + q * 4 + r;
      float* op = out + row * 1024 + colbase + wn + lr;
#pragma unroll
      for (int j = 0; j < 4; j++) op[j * 16] = acc[i][j][r];
    }
  }
}

// ---------------------------------------------------------------- phase 2
// hbuf layout (u16): [parity 2][part hi/lo 2][cluster 4][16384]
//   element (m,k) at (k>>3)*128 + m*8 + (k&7)  -> A-frag dwordx4-ready.
__global__ __launch_bounds__(256) void rnn_scan_kernel(const float* __restrict__ R,
                                                       float* __restrict__ out,
                                                       unsigned short* __restrict__ hbuf,
                                                       unsigned int* __restrict__ flags) {
  const int tid = threadIdx.x;
  const int lane = tid & 63;
  const int wv = tid >> 6;        // k-quarter 0..3
  const int q = lane >> 4;
  const int lr = lane & 15;
  const int cluster = blockIdx.x & 3;
  const int cg = blockIdx.x >> 2; // col-group 0..31

  // persistent W fragments: B[k][n] frag: lane n=lr, k = q*8+j
  short8 w[2][8];
#pragma unroll
  for (int nt = 0; nt < 2; nt++) {
    int col = cg * 32 + nt * 16 + lr;
#pragma unroll
    for (int cc = 0; cc < 8; cc++) {
      int k0 = wv * 256 + cc * 32 + q * 8;
      short8 t8;
#pragma unroll
      for (int j = 0; j < 8; j++)
        t8[j] = (short)f2bf_rne(R[(long)(k0 + j) * 1024 + col]);
      w[nt][cc] = t8;
    }
  }

  __shared__ float red[4 * 2 * 64 * 4];  // [wave][ntile][lane][reg] 8 KB
  unsigned int* myflag = flags + cluster * 64;  // 256B-padded counters
  const int m_lo = tid >> 5;   // 0..7
  const int myn = tid & 31;
  const int off0 = (wv * 32 + q) * 128 + lr * 8;  // cc=0 frag offset (u16)

  for (int t = 0; t < 512; ++t) {
    f32x4 acc0 = (f32x4)0.f, acc1 = (f32x4)0.f;
    if (t > 0) {
      const unsigned short* hb = hbuf + (size_t)((((t - 1) & 1) * 2 + 0) * 4 + cluster) * 16384;
      const unsigned short* lb = hbuf + (size_t)((((t - 1) & 1) * 2 + 1) * 4 + cluster) * 16384;
      const unsigned short* a0 = hb + off0;          // cc 0..3 (+1024B steps)
      const unsigned short* a4 = a0 + 2048;          // cc 4..7
      const unsigned short* b0 = lb + off0;
      const unsigned short* b4 = b0 + 2048;
      short8 ah[8], al[8];
      // all 16 coherent loads + the waitcnt in ONE asm block: MFMA operands
      // are defs of this block, so nothing can consume them before vmcnt(0).
      asm volatile(
          "global_load_dwordx4 %0,  %16, off sc0 sc1\n\t"
          "global_load_dwordx4 %1,  %16, off offset:1024 sc0 sc1\n\t"
          "global_load_dwordx4 %2,  %16, off offset:2048 sc0 sc1\n\t"
          "global_load_dwordx4 %3,  %16, off offset:3072 sc0 sc1\n\t"
          "global_load_dwordx4 %4,  %17, off sc0 sc1\n\t"
          "global_load_dwordx4 %5,  %17, off offset:1024 sc0 sc1\n\t"
          "global_load_dwordx4 %6,  %17, off offset:2048 sc0 sc1\n\t"
          "global_load_dwordx4 %7,  %17, off offset:3072 sc0 sc1\n\t"
          "global_load_dwordx4 %8,  %18, off sc0 sc1\n\t"
          "global_load_dwordx4 %9,  %18, off offset:1024 sc0 sc1\n\t"
          "global_load_dwordx4 %10, %18, off offset:2048 sc0 sc1\n\t"
          "global_load_dwordx4 %11, %18, off offset:3072 sc0 sc1\n\t"
          "global_load_dwordx4 %12, %19, off sc0 sc1\n\t"
          "global_load_dwordx4 %13, %19, off offset:1024 sc0 sc1\n\t"
          "global_load_dwordx4 %14, %19, off offset:2048 sc0 sc1\n\t"
          "global_load_dwordx4 %15, %19, off offset:3072 sc0 sc1\n\t"
          "s_waitcnt vmcnt(0)"
          : "=&v"(ah[0]), "=&v"(ah[1]), "=&v"(ah[2]), "=&v"(ah[3]),
            "=&v"(ah[4]), "=&v"(ah[5]), "=&v"(ah[6]), "=&v"(ah[7]),
            "=&v"(al[0]), "=&v"(al[1]), "=&v"(al[2]), "=&v"(al[3]),
            "=&v"(al[4]), "=&v"(al[5]), "=&v"(al[6]), "=&v"(al[7])
          : "v"(a0), "v"(a4), "v"(b0), "v"(b4)
          : "memory");
#pragma unroll
      for (int cc = 0; cc < 8; cc++) {
        acc0 = __builtin_amdgcn_mfma_f32_16x16x32_bf16(ah[cc], w[0][cc], acc0, 0, 0, 0);
        acc0 = __builtin_amdgcn_mfma_f32_16x16x32_bf16(al[cc], w[0][cc], acc0, 0, 0, 0);
        acc1 = __builtin_amdgcn_mfma_f32_16x16x32_bf16(ah[cc], w[1][cc], acc1, 0, 0, 0);
        acc1 = __builtin_amdgcn_mfma_f32_16x16x32_bf16(al[cc], w[1][cc], acc1, 0, 0, 0);
      }
    }
    // 4-way k-split reduction through LDS
    *(f32x4*)&red[((wv * 2 + 0) * 64 + lane) * 4] = acc0;
    *(f32x4*)&red[((wv * 2 + 1) * 64 + lane) * 4] = acc1;
    __syncthreads();
#pragma unroll
    for (int mi = 0; mi < 2; ++mi) {
      int m = m_lo + mi * 8;
      int nt = myn >> 4;
      int ln = (myn & 15) + ((m >> 2) & 3) * 16;
      int r = m & 3;
      float s = red[((0 * 2 + nt) * 64 + ln) * 4 + r] + red[((1 * 2 + nt) * 64 + ln) * 4 + r] +
                red[((2 * 2 + nt) * 64 + ln) * 4 + r] + red[((3 * 2 + nt) * 64 + ln) * 4 + r];
      long orow = (long)(cluster * 16 + m) * 512 + t;
      float* op = out + orow * 1024 + cg * 32 + myn;
      float h = s + *op;          // xk_t (phase-1 result, owned by this WG)
      h = fmaxf(h, 0.0f);
      *op = h;                    // final output h_t, in place (plain, cached)
      unsigned short hi = f2bf_rne(h);
      float hf = __uint_as_float(((unsigned)hi) << 16);
      unsigned short lo = f2bf_rne(h - hf);
      int k = cg * 32 + myn;
      int off = (k >> 3) * 128 + m * 8 + (k & 7);
      st_g16_cc(hbuf + (size_t)(((t & 1) * 2 + 0) * 4 + cluster) * 16384 + off, hi);
      st_g16_cc(hbuf + (size_t)(((t & 1) * 2 + 1) * 4 + cluster) * 16384 + off, lo);
    }
    if (t < 511) {
      wait_vm0();                 // h stores complete at coherence point
      __syncthreads();            // all waves of this WG have stored
      if (tid == 0) {
        flag_add_cc(myflag, 1u);
        unsigned target = 32u * (unsigned)(t + 1);
        while (ld_flag_cc(myflag) < target) {
          __builtin_amdgcn_s_sleep(1);
        }
      }
      __syncthreads();
    }
  }
}

extern "C" void kernel_launch(void* const* d_in, const int* in_sizes, int n_in,
                              void* d_out, int out_size, void* d_ws, size_t ws_size,
                              hipStream_t stream) {
  const float* x = (const float*)d_in[0];
  const float* kern = (const float*)d_in[1];
  const float* R = (const float*)d_in[2];
  float* out = (float*)d_out;

  // ws: [0, 512KB) h ping-pong hi/lo buffers; [512KB, +1KB) barrier flags
  unsigned short* hbuf = (unsigned short*)d_ws;
  unsigned int* flags = (unsigned int*)((char*)d_ws + (size_t)2 * 2 * 4 * 16384 * sizeof(unsigned short));
  hipMemsetAsync(flags, 0, 1024, stream);

  dim3 g1(8, 256), b1(256);
  xproj_kernel<<<g1, b1, 0, stream>>>(x, kern, out);
  rnn_scan_kernel<<<128, 256, 0, stream>>>(R, out, hbuf, flags);
}